// Round 11
// baseline (27517.230 us; speedup 1.0000x reference)
//
#include <hip/hip_runtime.h>
#include <hip/hip_fp16.h>

// ---------------- parameters (all inputs fp32; output fp32) ----------------
struct P19 {
  const float *src;
  const float *eWih0, *eWhh0, *ebih0, *ebhh0;
  const float *eWih1, *eWhh1, *ebih1, *ebhh1;
  const float *dWih0, *dWhh0, *dbih0, *dbhh0;
  const float *dWih1, *dWhh1, *dbih1, *dbhh1;
  const float *fcW, *fcb;
  float *out;
  float *ws;
};

typedef _Float16 h2v __attribute__((ext_vector_type(2)));

__device__ __forceinline__ float sigf(float x) { return 1.f / (1.f + __expf(-x)); }

__device__ __forceinline__ unsigned packh(float a, float b2) {
  __half2 h2 = __floats2half2_rn(a, b2);
  return *(const unsigned *)&h2;
}

// Uncached (L3 coherence-point) accessors: agent-scope relaxed atomics emit
// sc0+sc1 -> bypass L1/L2, no wbl2/inv fences (the r10 win). 4B and 8B forms.
__device__ __forceinline__ unsigned ldh(const unsigned *p) {
  return __hip_atomic_load(p, __ATOMIC_RELAXED, __HIP_MEMORY_SCOPE_AGENT);
}
__device__ __forceinline__ void sth(unsigned *p, unsigned v) {
  __hip_atomic_store(p, v, __ATOMIC_RELAXED, __HIP_MEMORY_SCOPE_AGENT);
}
__device__ __forceinline__ void sthf(float *p, float v) {
  __hip_atomic_store(p, v, __ATOMIC_RELAXED, __HIP_MEMORY_SCOPE_AGENT);
}
__device__ __forceinline__ uint2 ldh2(const unsigned *p) {
  unsigned long long v = __hip_atomic_load((const unsigned long long *)p,
                                           __ATOMIC_RELAXED, __HIP_MEMORY_SCOPE_AGENT);
  uint2 r; r.x = (unsigned)v; r.y = (unsigned)(v >> 32); return r;
}
__device__ __forceinline__ void sth2(unsigned *p, unsigned lo, unsigned hi) {
  unsigned long long v = ((unsigned long long)hi << 32) | (unsigned long long)lo;
  __hip_atomic_store((unsigned long long *)p, v, __ATOMIC_RELAXED, __HIP_MEMORY_SCOPE_AGENT);
}
__device__ __forceinline__ float2 ldhf2(const float *p) {
  union { unsigned long long u; float2 f; } c;
  c.u = __hip_atomic_load((const unsigned long long *)p, __ATOMIC_RELAXED,
                          __HIP_MEMORY_SCOPE_AGENT);
  return c.f;
}

__device__ __forceinline__ float dot2(unsigned h, unsigned w, float acc) {
#if __has_builtin(__builtin_amdgcn_fdot2)
  return __builtin_amdgcn_fdot2(*(h2v *)&h, *(h2v *)&w, acc, false);
#else
  float2 hf = __half22float2(*(const __half2 *)&h);
  float2 wf = __half22float2(*(const __half2 *)&w);
  return fmaf(hf.x, wf.x, fmaf(hf.y, wf.y, acc));
#endif
}

// ---- split-phase fenceless grid barrier; only wave3 polls (4 flags/lane) --
__device__ __forceinline__ void arrive(unsigned *flags, unsigned gen, int tid, int blk) {
  __syncthreads();  // drains vmcnt per wave: all agent-stores are in L3
  if (tid == 0) sth(flags + blk * 32, gen);
}
__device__ __forceinline__ void waitbar(unsigned *flags, unsigned gen, int tid) {
  if ((tid >> 6) == 3) {
    int l = tid & 63, g = 0;
    for (;;) {
      unsigned a = ldh(flags + (4 * l + 0) * 32);
      unsigned b = ldh(flags + (4 * l + 1) * 32);
      unsigned c = ldh(flags + (4 * l + 2) * 32);
      unsigned d = ldh(flags + (4 * l + 3) * 32);
      if (min(min(a, b), min(c, d)) >= gen) break;
      __builtin_amdgcn_s_sleep(4);
      if (++g > (1 << 16)) break;  // safety: never deadlock the bench
    }
  }
  __syncthreads();
}

// 16 dot2 from one h-dword-pair (2 batch cols) and 2 b128 weight broadcasts.
// B[u*8 + g*2 + p]: u=unit(2), g=gate(4), p=batch-in-pair(2).
#define DOT8(B, h, w0, w1) {                                          \
  (B)[0] = dot2(h.x, w0.x, (B)[0]);   (B)[1] = dot2(h.y, w0.x, (B)[1]);   \
  (B)[2] = dot2(h.x, w0.y, (B)[2]);   (B)[3] = dot2(h.y, w0.y, (B)[3]);   \
  (B)[4] = dot2(h.x, w0.z, (B)[4]);   (B)[5] = dot2(h.y, w0.z, (B)[5]);   \
  (B)[6] = dot2(h.x, w0.w, (B)[6]);   (B)[7] = dot2(h.y, w0.w, (B)[7]);   \
  (B)[8] = dot2(h.x, w1.x, (B)[8]);   (B)[9] = dot2(h.y, w1.x, (B)[9]);   \
  (B)[10] = dot2(h.x, w1.y, (B)[10]); (B)[11] = dot2(h.y, w1.y, (B)[11]); \
  (B)[12] = dot2(h.x, w1.z, (B)[12]); (B)[13] = dot2(h.y, w1.z, (B)[13]); \
  (B)[14] = dot2(h.x, w1.w, (B)[14]); (B)[15] = dot2(h.y, w1.w, (B)[15]); }

// quarter-dots: wave covers 64 k2 (its k-quarter), lane covers b=2l,2l+1.
// Per k2 per matrix: 2 ds_read_b128 -> 16 dot2 (VALU-bound; was 4 dot2/read).
__device__ __forceinline__ void dotp1(float *A, const uint4 *__restrict__ wq,
                                      const unsigned *__restrict__ hq) {
  uint2 ca[16], cb[16];
#pragma unroll
  for (int c = 0; c < 16; ++c) ca[c] = ldh2(hq + c * 128);
  for (int j = 0; j < 4; j += 2) {
#pragma unroll
    for (int c = 0; c < 16; ++c) cb[c] = ldh2(hq + ((j + 1) * 16 + c) * 128);
#pragma unroll
    for (int c = 0; c < 16; ++c) {
      int k2 = j * 16 + c;
      uint4 w0 = wq[k2 * 2], w1 = wq[k2 * 2 + 1];
      uint2 h = ca[c];
      DOT8(A, h, w0, w1)
    }
#pragma unroll
    for (int c = 0; c < 16; ++c) ca[c] = ldh2(hq + ((((j + 2) & 3)) * 16 + c) * 128);
#pragma unroll
    for (int c = 0; c < 16; ++c) {
      int k2 = (j + 1) * 16 + c;
      uint4 w0 = wq[k2 * 2], w1 = wq[k2 * 2 + 1];
      uint2 h = cb[c];
      DOT8(A, h, w0, w1)
    }
  }
}
__device__ __forceinline__ void dotp2(float *A /*32*/, const uint4 *__restrict__ wa,
                                      const uint4 *__restrict__ wb,
                                      const unsigned *__restrict__ hq) {
  uint2 ca[16], cb[16];
#pragma unroll
  for (int c = 0; c < 16; ++c) ca[c] = ldh2(hq + c * 128);
  for (int j = 0; j < 4; j += 2) {
#pragma unroll
    for (int c = 0; c < 16; ++c) cb[c] = ldh2(hq + ((j + 1) * 16 + c) * 128);
#pragma unroll
    for (int c = 0; c < 16; ++c) {
      int k2 = j * 16 + c;
      uint2 h = ca[c];
      uint4 w0 = wa[k2 * 2], w1 = wa[k2 * 2 + 1];
      DOT8(A, h, w0, w1)
      uint4 v0 = wb[k2 * 2], v1 = wb[k2 * 2 + 1];
      DOT8(A + 16, h, v0, v1)
    }
#pragma unroll
    for (int c = 0; c < 16; ++c) ca[c] = ldh2(hq + ((((j + 2) & 3)) * 16 + c) * 128);
#pragma unroll
    for (int c = 0; c < 16; ++c) {
      int k2 = (j + 1) * 16 + c;
      uint2 h = cb[c];
      uint4 w0 = wa[k2 * 2], w1 = wa[k2 * 2 + 1];
      DOT8(A, h, w0, w1)
      uint4 v0 = wb[k2 * 2], v1 = wb[k2 * 2 + 1];
      DOT8(A + 16, h, v0, v1)
    }
  }
}

// cross-wave partial exchange (float4, pad 20 floats keeps 16B alignment)
__device__ __forceinline__ void rwrite(float *dst, const float *A) {
#pragma unroll
  for (int q = 0; q < 4; ++q)
    *(float4 *)&dst[q * 4] = make_float4(A[q * 4], A[q * 4 + 1], A[q * 4 + 2], A[q * 4 + 3]);
}
__device__ __forceinline__ void rread3(float (*B)[64][20], int l, float *G) {
#pragma unroll
  for (int wi = 0; wi < 3; ++wi)
#pragma unroll
    for (int q = 0; q < 4; ++q) {
      float4 v = *(const float4 *)&B[wi][l][q * 4];
      G[q * 4] += v.x; G[q * 4 + 1] += v.y; G[q * 4 + 2] += v.z; G[q * 4 + 3] += v.w;
    }
}

// cell update for 2 units x 2 batch (G pre-biased); packs h into 2 dwords
__device__ __forceinline__ void cell2(const float *G, float c[2][2], unsigned hv[2]) {
  float h[2][2];
#pragma unroll
  for (int u = 0; u < 2; ++u)
#pragma unroll
    for (int p = 0; p < 2; ++p) {
      float ig = sigf(G[u * 8 + 0 + p]);
      float fg = sigf(G[u * 8 + 2 + p]);
      float gg = tanhf(G[u * 8 + 4 + p]);
      float og = sigf(G[u * 8 + 6 + p]);
      c[u][p] = fg * c[u][p] + ig * gg;
      h[u][p] = og * tanhf(c[u][p]);
    }
  hv[0] = packh(h[0][0], h[1][0]);
  hv[1] = packh(h[0][1], h[1][1]);
}

__device__ __forceinline__ void fc_emit(const unsigned *__restrict__ h1buf,
                                        const float *__restrict__ fcW,
                                        const float *__restrict__ fcb,
                                        float *__restrict__ out, int sIdx,
                                        int tid, int blk) {
  int q = tid >> 6, l = tid & 63;
  if (q < 3) {
    int o = blk * 3 + q, j = o >> 7, bb = o & 127;
    const unsigned *hc = h1buf + bb;
    const float2 *fw = (const float2 *)(fcW + j * 512);
    float acc = 0.f;
#pragma unroll
    for (int r = 0; r < 4; ++r) {
      int k2 = l + r * 64;
      unsigned d = ldh(hc + k2 * 128);
      float2 hf = __half22float2(*(const __half2 *)&d);
      float2 wv = fw[k2];
      acc = fmaf(wv.x, hf.x, acc);
      acc = fmaf(wv.y, hf.y, acc);
    }
#pragma unroll
    for (int off = 32; off; off >>= 1) acc += __shfl_down(acc, off, 64);
    if (l == 0) out[((size_t)bb * 256 + sIdx) * 6 + j] = acc + fcb[j];
  }
}

// 256 threads = 4 waves: wave w = k-quarter; lane l = batch-pair (2l, 2l+1).
// Owners: wave0 = layer0 cell (c0), wave2 = layer1 cell (c1); wave3 polls.
__global__ __launch_bounds__(256, 1) void seq2seq_kernel(P19 p) {
  const int tid = threadIdx.x;
  const int blk = blockIdx.x;
  const int w = tid >> 6;
  const int l = tid & 63;

  float *ws = p.ws;
  unsigned *flags = (unsigned *)ws;  // 256 flags, 128B-spaced
  unsigned *hpB = (unsigned *)(ws + 8256);
  unsigned *hp0r[2] = {hpB, hpB + 32768};           // h0 parity, [k2][b]
  unsigned *hp1r[2] = {hpB + 65536, hpB + 98304};   // h1 parity
  float *outp = ws + 8256 + 131072;                 // dec seed [j][b] 6*128
  float *srcT = outp + 768;                         // [t][i][b] 256*6*128

  // LDS: weights 56KB + redux 45KB (+misc) = ~102KB -> forces 1 block/CU
  __shared__ __align__(16) uint4 wl4[3584];   // 7 matrices x 256 k2 x 2 uint4
  __shared__ __align__(16) float rb[3][3][64][20];  // set, writer, lane, 16+pad
  __shared__ float wxe[48], wxd[48], bbuf[40];
  unsigned *wl1 = (unsigned *)wl4;

  {  // ---- stage weights (fp16 pairs) into LDS, once ----
    const float *mats[6] = {p.eWhh0, p.eWih1, p.eWhh1, p.dWhh0, p.dWih1, p.dWhh1};
    for (int e = tid; e < 12288; e += 256) {
      int k2 = e & 255, r = e >> 8;       // r 0..47
      int g = r & 3, uu = (r >> 2) & 1, m = r >> 3;
      const float *row = mats[m] + (size_t)(g * 512 + blk * 2 + uu) * 512;
      wl1[(m * 512 + k2 * 2 + uu) * 4 + g] = packh(row[2 * k2], row[2 * k2 + 1]);
    }
    for (int e = tid; e < 2048; e += 256) {  // W' = dec_Wih0 @ fcW -> slot 6
      int uu = e >> 10, rem = e & 1023, g = rem & 3, k2 = rem >> 2;
      const float *wr = p.dWih0 + (size_t)(g * 512 + blk * 2 + uu) * 6;
      float v0 = 0.f, v1 = 0.f;
#pragma unroll
      for (int i = 0; i < 6; ++i) {
        v0 = fmaf(wr[i], p.fcW[i * 512 + 2 * k2], v0);
        v1 = fmaf(wr[i], p.fcW[i * 512 + 2 * k2 + 1], v1);
      }
      wl1[(6 * 512 + k2 * 2 + uu) * 4 + g] = packh(v0, v1);
    }
    if (tid < 40) {  // fused biases: be0|be1|bd1|b''|bd0
      int f = tid >> 3, k = tid & 7, uu = k >> 2, g = k & 3;
      int r2 = g * 512 + blk * 2 + uu;
      float v;
      if (f == 0) v = p.ebih0[r2] + p.ebhh0[r2];
      else if (f == 1) v = p.ebih1[r2] + p.ebhh1[r2];
      else if (f == 2) v = p.dbih1[r2] + p.dbhh1[r2];
      else {
        v = p.dbih0[r2] + p.dbhh0[r2];
        if (f == 3)
#pragma unroll
          for (int i = 0; i < 6; ++i) v = fmaf(p.dWih0[(size_t)r2 * 6 + i], p.fcb[i], v);
      }
      bbuf[tid] = v;
    } else if (tid >= 64 && tid < 112) {
      int idx = tid - 64, uu = idx / 24, rem = idx % 24, g = rem / 6, i = rem % 6;
      wxe[idx] = p.eWih0[(size_t)(g * 512 + blk * 2 + uu) * 6 + i];
    } else if (tid >= 128 && tid < 176) {
      int idx = tid - 128, uu = idx / 24, rem = idx % 24, g = rem / 6, i = rem % 6;
      wxd[idx] = p.dWih0[(size_t)(g * 512 + blk * 2 + uu) * 6 + i];
    }
  }
  // ---- init: transpose src -> srcT; seed decoder input (agent stores) ----
  for (int e = blk * 256 + tid; e < 196608; e += 65536) {
    int bb = e & 127, rest = e >> 7, i = rest % 6, t = rest / 6;
    sthf(&srcT[t * 768 + i * 128 + bb], p.src[((size_t)bb * 256 + t) * 6 + i]);
  }
  {
    int g0 = blk * 256 + tid;
    if (g0 < 768) {
      int bb = g0 & 127, i = g0 >> 7;
      sthf(&outp[i * 128 + bb], p.src[((size_t)bb * 256 + 255) * 6 + i]);
    }
  }
  float c0[2][2] = {{0.f, 0.f}, {0.f, 0.f}};  // live in wave0 lanes
  float c1[2][2] = {{0.f, 0.f}, {0.f, 0.f}};  // live in wave2 lanes
  unsigned gen = 1;
  arrive(flags, gen, tid, blk);
  waitbar(flags, gen, tid);

#define WQn(m) (wl4 + (m) * 512 + w * 128)
#define HSTn(buf) ((const unsigned *)(buf) + w * 8192 + 2 * l)

  // ================= encoder: layer0 & layer1 pipelined (lag 1) ============
  for (int t = 0; t <= 256; ++t) {
    float A2[32], A1[16];
#pragma unroll
    for (int i = 0; i < 32; ++i) A2[i] = 0.f;
#pragma unroll
    for (int i = 0; i < 16; ++i) A1[i] = 0.f;
    dotp2(A2, WQn(0), WQn(1), HSTn(hp0r[t & 1]));   // eWhh0 + eWih1 share h0[t-1]
    dotp1(A1, WQn(2), HSTn(hp1r[(t + 1) & 1]));     // eWhh1 @ h1[t-2]
    if (w != 0) rwrite(&rb[0][w - 1][l][0], A2);                       // set0
    if (w != 2) {
      int wi = w > 2 ? w - 1 : w;
      rwrite(&rb[1][wi][l][0], A2 + 16);                               // set1
      rwrite(&rb[2][wi][l][0], A1);                                    // set2
    }
    __syncthreads();
    if (w == 0 && t < 256) {  // layer0 cell (owner wave0)
      float G[16];
#pragma unroll
      for (int i = 0; i < 16; ++i) G[i] = A2[i];
      rread3(rb[0], l, G);
      float2 xv[6];
#pragma unroll
      for (int i = 0; i < 6; ++i)
        xv[i] = *(const float2 *)&srcT[t * 768 + i * 128 + 2 * l];
#pragma unroll
      for (int u = 0; u < 2; ++u)
#pragma unroll
        for (int g = 0; g < 4; ++g) {
          float a0 = bbuf[u * 4 + g], a1 = a0;
#pragma unroll
          for (int i = 0; i < 6; ++i) {
            float wv = wxe[u * 24 + g * 6 + i];
            a0 = fmaf(wv, xv[i].x, a0);
            a1 = fmaf(wv, xv[i].y, a1);
          }
          G[u * 8 + g * 2 + 0] += a0;
          G[u * 8 + g * 2 + 1] += a1;
        }
      unsigned hv[2];
      cell2(G, c0, hv);
      sth2(&hp0r[(t + 1) & 1][blk * 128 + 2 * l], hv[0], hv[1]);
    }
    if (w == 2 && t >= 1) {  // layer1 cell (owner wave2)
      float G[16];
#pragma unroll
      for (int i = 0; i < 16; ++i) G[i] = A2[16 + i] + A1[i];
      rread3(rb[1], l, G);
      rread3(rb[2], l, G);
#pragma unroll
      for (int u = 0; u < 2; ++u)
#pragma unroll
        for (int g = 0; g < 4; ++g) {
          float bs = bbuf[8 + u * 4 + g];
          G[u * 8 + g * 2 + 0] += bs;
          G[u * 8 + g * 2 + 1] += bs;
        }
      unsigned hv[2];
      cell2(G, c1, hv);
      sth2(&hp1r[t & 1][blk * 128 + 2 * l], hv[0], hv[1]);
    }
    arrive(flags, ++gen, tid, blk);
    waitbar(flags, gen, tid);
  }
  // enc final: h0 in hp0r[0], h1 in hp1r[0]; c0 in wave0, c1 in wave2.

  // ========== decoder: 2 rounds/step, pre-dots hide barrier waits ==========
  for (int s = 0; s < 256; ++s) {
    // ---- R_A: dec layer0 (+ W'@h1 fused fc; saves Whh1d partial for R_B) --
    float A0[16];
#pragma unroll
    for (int i = 0; i < 16; ++i) A0[i] = 0.f;
    dotp1(A0, WQn(3), HSTn(hp0r[s & 1]));  // pre-wait: h0[s-1], 2 gens old
    if (s) waitbar(flags, gen, tid);
    float A12[32];
#pragma unroll
    for (int i = 0; i < 32; ++i) A12[i] = 0.f;
    if (s == 0) {
      dotp1(A12 + 16, WQn(5), HSTn(hp1r[0]));   // Whh1d partial only
    } else {
      dotp2(A12, WQn(6), WQn(5), HSTn(hp1r[s & 1]));  // W' + Whh1d share h1
      fc_emit(hp1r[s & 1], p.fcW, p.fcb, p.out, s - 1, tid, blk);
    }
    if (w != 0) {
      rwrite(&rb[0][w - 1][l][0], A0);
      rwrite(&rb[1][w - 1][l][0], A12);
    }
    __syncthreads();
    if (w == 0) {  // layer0 cell
      float G[16];
#pragma unroll
      for (int i = 0; i < 16; ++i) G[i] = A0[i] + A12[i];
      rread3(rb[0], l, G);
      rread3(rb[1], l, G);
      if (s == 0) {
        float2 xv[6];
#pragma unroll
        for (int i = 0; i < 6; ++i) xv[i] = ldhf2(&outp[i * 128 + 2 * l]);
#pragma unroll
        for (int u = 0; u < 2; ++u)
#pragma unroll
          for (int g = 0; g < 4; ++g) {
            float a0 = bbuf[32 + u * 4 + g], a1 = a0;
#pragma unroll
            for (int i = 0; i < 6; ++i) {
              float wv = wxd[u * 24 + g * 6 + i];
              a0 = fmaf(wv, xv[i].x, a0);
              a1 = fmaf(wv, xv[i].y, a1);
            }
            G[u * 8 + g * 2 + 0] += a0;
            G[u * 8 + g * 2 + 1] += a1;
          }
      } else {
#pragma unroll
        for (int u = 0; u < 2; ++u)
#pragma unroll
          for (int g = 0; g < 4; ++g) {
            float bs = bbuf[24 + u * 4 + g];  // b'' (bias + Wih0d@fcb)
            G[u * 8 + g * 2 + 0] += bs;
            G[u * 8 + g * 2 + 1] += bs;
          }
      }
      unsigned hv[2];
      cell2(G, c0, hv);
      sth2(&hp0r[(s + 1) & 1][blk * 128 + 2 * l], hv[0], hv[1]);
    }
    arrive(flags, ++gen, tid, blk);
    // ---- R_B: dec layer1 = saved Whh1d partial + Wih1d @ h0[s] ------------
    waitbar(flags, gen, tid);
    float A4[16];
#pragma unroll
    for (int i = 0; i < 16; ++i) A4[i] = A12[16 + i];
    dotp1(A4, WQn(4), HSTn(hp0r[(s + 1) & 1]));
    if (w != 2) {
      int wi = w > 2 ? w - 1 : w;
      rwrite(&rb[2][wi][l][0], A4);
    }
    __syncthreads();
    if (w == 2) {  // layer1 cell
      float G[16];
#pragma unroll
      for (int i = 0; i < 16; ++i) G[i] = A4[i];
      rread3(rb[2], l, G);
#pragma unroll
      for (int u = 0; u < 2; ++u)
#pragma unroll
        for (int g = 0; g < 4; ++g) {
          float bs = bbuf[16 + u * 4 + g];
          G[u * 8 + g * 2 + 0] += bs;
          G[u * 8 + g * 2 + 1] += bs;
        }
      unsigned hv[2];
      cell2(G, c1, hv);
      sth2(&hp1r[(s + 1) & 1][blk * 128 + 2 * l], hv[0], hv[1]);
    }
    arrive(flags, ++gen, tid, blk);
  }
  waitbar(flags, gen, tid);
  fc_emit(hp1r[0], p.fcW, p.fcb, p.out, 255, tid, blk);  // tail out[255]
}

extern "C" void kernel_launch(void *const *d_in, const int *in_sizes, int n_in,
                              void *d_out, int out_size, void *d_ws, size_t ws_size,
                              hipStream_t stream) {
  (void)in_sizes; (void)n_in; (void)out_size; (void)ws_size;
  P19 p;
  p.src = (const float *)d_in[0];
  p.eWih0 = (const float *)d_in[1];  p.eWhh0 = (const float *)d_in[2];
  p.ebih0 = (const float *)d_in[3];  p.ebhh0 = (const float *)d_in[4];
  p.eWih1 = (const float *)d_in[5];  p.eWhh1 = (const float *)d_in[6];
  p.ebih1 = (const float *)d_in[7];  p.ebhh1 = (const float *)d_in[8];
  p.dWih0 = (const float *)d_in[9];  p.dWhh0 = (const float *)d_in[10];
  p.dbih0 = (const float *)d_in[11]; p.dbhh0 = (const float *)d_in[12];
  p.dWih1 = (const float *)d_in[13]; p.dWhh1 = (const float *)d_in[14];
  p.dbih1 = (const float *)d_in[15]; p.dbhh1 = (const float *)d_in[16];
  p.fcW = (const float *)d_in[17];   p.fcb = (const float *)d_in[18];
  p.out = (float *)d_out;
  p.ws = (float *)d_ws;

  // zero flags + 4 packed-h parity buffers (outp/srcT written by kernel init)
  hipMemsetAsync(d_ws, 0, (size_t)(8256 + 4 * 32768) * sizeof(float), stream);
  seq2seq_kernel<<<dim3(256), dim3(256), 0, stream>>>(p);
}